// Round 4
// baseline (167.641 us; speedup 1.0000x reference)
//
#include <hip/hip_runtime.h>

// ---------------- types & helpers ----------------
typedef __attribute__((ext_vector_type(8))) short short8;   // 8 bf16 (4 VGPRs)
typedef __attribute__((ext_vector_type(4))) float f32x4;

#define LEAKY_F 0.3f

typedef __attribute__((address_space(3))) void lds_t;
typedef __attribute__((address_space(1))) void gmem_t;
#define G2L(g, l) __builtin_amdgcn_global_load_lds((const gmem_t*)(g), (lds_t*)(l), 16, 0, 0)

__device__ __forceinline__ unsigned short f2bf(float f) {
    union { float f; unsigned u; } v; v.f = f;
    unsigned u = v.u;
    return (unsigned short)((u + 0x7fffu + ((u >> 16) & 1u)) >> 16);  // RNE
}
__device__ __forceinline__ float bf2f(unsigned short u) {
    union { unsigned u; float f; } v; v.u = ((unsigned)u) << 16; return v.f;
}

// ---------------- cast x f32 -> bf16 into padded [32][1028][512] ----------------
__global__ void cast_pad_x(const float* __restrict__ in, unsigned short* __restrict__ out) {
    int i = blockIdx.x * 256 + threadIdx.x;     // 8 elems per thread
    long g = (long)i * 8;
    int row = (int)(g >> 9);                    // 0..32767 (b*1024+t)
    int b = row >> 10;
    long o = ((long)(row + (b << 2) + 2) << 9) + (g & 511);
    const float4* p = (const float4*)(in + g);
    float4 a = p[0], c = p[1];
    union { unsigned short s[8]; uint4 v; } u;
    u.s[0] = f2bf(a.x); u.s[1] = f2bf(a.y); u.s[2] = f2bf(a.z); u.s[3] = f2bf(a.w);
    u.s[4] = f2bf(c.x); u.s[5] = f2bf(c.y); u.s[6] = f2bf(c.z); u.s[7] = f2bf(c.w);
    *(uint4*)(out + o) = u.v;
}

// ---------------- zero halo rows {0,1,1026,1027} of padded buffer ----------------
__global__ void zero_pads(unsigned short* __restrict__ p, int cin) {
    int j = blockIdx.x * 256 + threadIdx.x;     // one uint4 (8 elems) per thread
    int upb = cin >> 1;                          // units per batch (4 rows * cin / 8)
    int b = j / upb, rem = j % upb;
    int upr = cin >> 3;                          // units per row
    int r4 = rem / upr;
    int col = (rem % upr) * 8;
    int rowp = (r4 < 2) ? r4 : (r4 + 1024);
    *(uint4*)(p + ((long)b * 1028 + rowp) * cin + col) = make_uint4(0u, 0u, 0u, 0u);
}

// ---------------- weight rearrange: [CH][CIN][5] -> [CH][5*CIN] bf16 ----------------
__global__ void prep_w(const float* __restrict__ w, unsigned short* __restrict__ out, int CIN, int n) {
    int i = blockIdx.x * 256 + threadIdx.x;
    if (i >= n) return;
    int ch = i / (CIN * 5);
    int rem = i % (CIN * 5);
    int tap = rem / CIN;
    int cin = rem % CIN;
    out[ch * (5 * CIN) + tap * CIN + cin] = f2bf(w[(ch * CIN + cin) * 5 + tap]);
}

// ---------------- conv-as-GEMM, 256x256 tile, 8-phase schedule ----------------
// A padded [32][1028][CIN] bf16; im2col linear. BM=256, BN=256, BK=64.
// 8 waves 2Mx4N, per-wave 128x64 (acc 8x4). 2 LDS buffers, 4 stage-chunks/tile
// (Bh0,Bh1,Ah0,Ah1 of t+1 issued in phases 1-4 of t), counted vmcnt.
template<int CIN, bool PRED>
__global__ __launch_bounds__(512, 1) void gemm_conv_fused(
    const unsigned short* __restrict__ A,
    const unsigned short* __restrict__ W,    // [256][5*CIN]
    const float* __restrict__ bias,
    const float* __restrict__ gam,
    const float* __restrict__ bet,
    const float* __restrict__ wlin,
    const float* __restrict__ blin,
    const unsigned char* __restrict__ mask,
    unsigned short* __restrict__ Yln,        // [32][1028][256] padded
    float* __restrict__ Ypred)               // [32768]
{
    constexpr int KW = 5 * CIN;
    constexpr int S  = KW / 64;
    __shared__ __align__(16) unsigned short smem[65536];   // 128 KB: A[2][16K] | B[2][16K]
    __shared__ float pb[1024];

    const int tid = threadIdx.x, lane = tid & 63, wid = tid >> 6;
    const int wm = wid >> 2, wn = wid & 3;
    const int blk = blockIdx.x;                 // 0..127
    const int bb = blk >> 2, tl0 = (blk & 3) << 8;
    const long rowbase = (long)bb * 1028 + tl0;

    // stage descriptors: per chunk-call c in {0,1}: unit u = c*512 + tid (16 B each).
    // LDS dest linear; global source k-seg pre-swizzled by (row&7) for the read side.
    long asrc[2], bsrc[2]; int udst[2];
    #pragma unroll
    for (int c = 0; c < 2; c++) {
        int u = c * 512 + tid;
        int r = u >> 3, sg = (u & 7) ^ (r & 7);
        asrc[c] = (rowbase + r) * (long)CIN + sg * 8;
        bsrc[c] = (long)r * KW + sg * 8;
        udst[c] = u * 8;
    }

    auto stageA = [&](int buf, int h, int kt) {
        const long k0 = (long)kt * 64 + (long)h * 128 * CIN;
        #pragma unroll
        for (int c = 0; c < 2; c++)
            G2L(A + asrc[c] + k0, &smem[buf * 16384 + h * 8192 + udst[c]]);
    };
    auto stageB = [&](int buf, int h, int kt) {
        const long k0 = (long)kt * 64 + (long)h * 128 * KW;
        #pragma unroll
        for (int c = 0; c < 2; c++)
            G2L(W + bsrc[c] + k0, &smem[32768 + buf * 16384 + h * 8192 + udst[c]]);
    };

    const int l15 = lane & 15, lhi = (lane >> 4) & 3, sw = l15 & 7;
    const int arow0 = wm * 128 + l15;
    const int brow0 = wn * 64 + l15;

    f32x4 acc[8][4] = {};
    short8 bg[4][2];

#define READ_B(buf)                                                             \
    _Pragma("unroll")                                                           \
    for (int n = 0; n < 4; n++)                                                 \
        _Pragma("unroll")                                                       \
        for (int kh = 0; kh < 2; kh++)                                          \
            bg[n][kh] = *(const short8*)&smem[32768 + (buf) * 16384 +           \
                (brow0 + n * 16) * 64 + ((((kh << 2) | lhi) ^ sw) << 3)];

#define PHASE(buf, mp, STAGE, VMW)                                              \
    {                                                                           \
        short8 af[2][2];                                                        \
        _Pragma("unroll")                                                       \
        for (int j = 0; j < 2; j++)                                             \
            _Pragma("unroll")                                                   \
            for (int kh = 0; kh < 2; kh++)                                      \
                af[j][kh] = *(const short8*)&smem[(buf) * 16384 +               \
                    (arow0 + ((mp) * 2 + j) * 16) * 64 + ((((kh << 2) | lhi) ^ sw) << 3)]; \
        STAGE;                                                                  \
        VMW;                                                                    \
        __builtin_amdgcn_s_barrier();                                           \
        asm volatile("s_waitcnt lgkmcnt(0)" ::: "memory");                      \
        __builtin_amdgcn_sched_barrier(0);                                      \
        __builtin_amdgcn_s_setprio(1);                                          \
        _Pragma("unroll")                                                       \
        for (int j = 0; j < 2; j++)                                             \
            _Pragma("unroll")                                                   \
            for (int n = 0; n < 4; n++)                                         \
                _Pragma("unroll")                                               \
                for (int kh = 0; kh < 2; kh++)                                  \
                    acc[(mp) * 2 + j][n] = __builtin_amdgcn_mfma_f32_16x16x32_bf16( \
                        af[j][kh], bg[n][kh], acc[(mp) * 2 + j][n], 0, 0, 0);   \
        __builtin_amdgcn_s_setprio(0);                                          \
        __builtin_amdgcn_sched_barrier(0);                                      \
        __builtin_amdgcn_s_barrier();                                           \
    }

    // prologue: tile 0's four chunks, oldest-first order = use order
    stageB(0, 0, 0); stageB(0, 1, 0); stageA(0, 0, 0); stageA(0, 1, 0);
    asm volatile("s_waitcnt vmcnt(2)" ::: "memory");
    __builtin_amdgcn_s_barrier();

    #pragma unroll 1
    for (int t = 0; t < S - 1; ++t) {
        const int b = t & 1, nb = b ^ 1;
        READ_B(b);
        PHASE(b, 0, stageB(nb, 0, t + 1), );
        PHASE(b, 1, stageB(nb, 1, t + 1), asm volatile("s_waitcnt vmcnt(4)" ::: "memory"));
        PHASE(b, 2, stageA(nb, 0, t + 1), );
        PHASE(b, 3, stageA(nb, 1, t + 1), asm volatile("s_waitcnt vmcnt(2)" ::: "memory"));
    }
    {   // tail tile S-1: no staging; drain A-h1 before phase 3 reads it
        const int b = (S - 1) & 1;
        READ_B(b);
        PHASE(b, 0, , );
        PHASE(b, 1, , asm volatile("s_waitcnt vmcnt(0)" ::: "memory"));
        PHASE(b, 2, , );
        PHASE(b, 3, , );
    }
#undef PHASE
#undef READ_B

    // ================= fused epilogue =================
    __syncthreads();
    if (tid < 256) {
        pb[tid]       = bias[tid];
        pb[256 + tid] = gam[tid];
        pb[512 + tid] = bet[tid];
        pb[768 + tid] = PRED ? wlin[tid] : 0.f;
    }
    __syncthreads();

    // acc -> LDS tile [256][256] bf16 (bias+leaky), 16B-unit XOR swizzle by row&7
    #pragma unroll
    for (int mm = 0; mm < 8; mm++) {
        #pragma unroll
        for (int n = 0; n < 4; n++) {
            const int col = wn * 64 + n * 16 + l15;
            const int u0 = col >> 3, ce = col & 7;
            const float bv = pb[col];
            #pragma unroll
            for (int q = 0; q < 4; q++) {
                const int row = wm * 128 + mm * 16 + lhi * 4 + q;
                float v = acc[mm][n][q] + bv;
                v = v > 0.f ? v : LEAKY_F * v;
                smem[row * 256 + ((u0 ^ (row & 7)) << 3) + ce] = f2bf(v);
            }
        }
    }
    __syncthreads();

    // per-row stats (4 lanes/row, two row-groups of 128)
    const int rid = tid >> 2, jq = tid & 3;
    #pragma unroll 1
    for (int ro = 0; ro < 2; ro++) {
        const int row = ro * 128 + rid;
        const int r7 = row & 7;
        float vals[8][8];
        float s1 = 0.f, s2 = 0.f, sgw = 0.f, sgc = 0.f, sbw = 0.f;
        #pragma unroll
        for (int u4 = 0; u4 < 8; u4++) {
            const int u = u4 * 4 + jq;
            short8 pk = *(const short8*)&smem[row * 256 + ((u ^ r7) << 3)];
            #pragma unroll
            for (int e = 0; e < 8; e++) {
                float v = bf2f((unsigned short)pk[e]);
                vals[u4][e] = v;
                s1 += v; s2 += v * v;
            }
            if (PRED) {
                const int c0 = u * 8;
                f32x4 ga = *(const f32x4*)&pb[256 + c0], gb = *(const f32x4*)&pb[260 + c0];
                f32x4 wa = *(const f32x4*)&pb[768 + c0], wb = *(const f32x4*)&pb[772 + c0];
                f32x4 ba = *(const f32x4*)&pb[512 + c0], bb2 = *(const f32x4*)&pb[516 + c0];
                #pragma unroll
                for (int e = 0; e < 4; e++) {
                    sgw += vals[u4][e] * ga[e] * wa[e] + vals[u4][e + 4] * gb[e] * wb[e];
                    sgc += ga[e] * wa[e] + gb[e] * wb[e];
                    sbw += ba[e] * wa[e] + bb2[e] * wb[e];
                }
            }
        }
        s1 += __shfl_xor(s1, 1); s1 += __shfl_xor(s1, 2);
        s2 += __shfl_xor(s2, 1); s2 += __shfl_xor(s2, 2);
        const float mean = s1 * (1.f / 256.f);
        const float var  = s2 * (1.f / 256.f) - mean * mean;
        const float rs   = rsqrtf(var + 1e-5f);
        const long grow  = (long)blk * 256 + row;

        if (PRED) {
            sgw += __shfl_xor(sgw, 1); sgw += __shfl_xor(sgw, 2);
            sgc += __shfl_xor(sgc, 1); sgc += __shfl_xor(sgc, 2);
            sbw += __shfl_xor(sbw, 1); sbw += __shfl_xor(sbw, 2);
            if (jq == 0) {
                float p = rs * (sgw - mean * sgc) + sbw + blin[0];
                if (mask[grow]) p = 0.f;
                Ypred[grow] = p;
            }
        } else {
            const int bnum = (int)(grow >> 10);
            const long prow = grow + (bnum << 2) + 2;
            #pragma unroll
            for (int u4 = 0; u4 < 8; u4++) {
                const int u = u4 * 4 + jq;
                const int c0 = u * 8;
                f32x4 ga = *(const f32x4*)&pb[256 + c0], gb = *(const f32x4*)&pb[260 + c0];
                f32x4 ba = *(const f32x4*)&pb[512 + c0], bb2 = *(const f32x4*)&pb[516 + c0];
                union { unsigned short s[8]; uint4 v; } o;
                #pragma unroll
                for (int e = 0; e < 4; e++) {
                    o.s[e]     = f2bf((vals[u4][e]     - mean) * rs * ga[e] + ba[e]);
                    o.s[e + 4] = f2bf((vals[u4][e + 4] - mean) * rs * gb[e] + bb2[e]);
                }
                *(uint4*)(Yln + prow * 256 + c0) = o.v;
            }
        }
    }
}

// ---------------- averaged-over-durations (exact reference algorithm) ----------------
__global__ void avg_kernel(const float* __restrict__ target, const int* __restrict__ dr,
                           float* __restrict__ outAvg) {
    __shared__ float vcum[4097];
    __shared__ float ncum[4097];
    __shared__ float sS[256];
    __shared__ float sC[256];
    __shared__ int   sI[256];
    int b = blockIdx.x, tid = threadIdx.x;
    const float* tb = target + b * 4096;
    float lv[16]; float ls = 0.f, lc = 0.f;
    #pragma unroll
    for (int j = 0; j < 16; j++) {
        float v = tb[tid * 16 + j]; lv[j] = v; ls += v; lc += (v != 0.f) ? 1.f : 0.f;
    }
    sS[tid] = ls; sC[tid] = lc;
    __syncthreads();
    for (int off = 1; off < 256; off <<= 1) {
        float a = 0.f, c2 = 0.f;
        if (tid >= off) { a = sS[tid - off]; c2 = sC[tid - off]; }
        __syncthreads();
        sS[tid] += a; sC[tid] += c2;
        __syncthreads();
    }
    float pS = tid ? sS[tid - 1] : 0.f, pC = tid ? sC[tid - 1] : 0.f;
    if (tid == 0) { vcum[0] = 0.f; ncum[0] = 0.f; }
    float run = pS, runc = pC;
    #pragma unroll
    for (int j = 0; j < 16; j++) {
        run += lv[j]; runc += (lv[j] != 0.f) ? 1.f : 0.f;
        vcum[tid * 16 + j + 1] = run; ncum[tid * 16 + j + 1] = runc;
    }
    const int* db = dr + b * 1024;
    int ld[4]; int lsum = 0;
    #pragma unroll
    for (int j = 0; j < 4; j++) { ld[j] = db[tid * 4 + j]; lsum += ld[j]; }
    sI[tid] = lsum;
    __syncthreads();
    for (int off = 1; off < 256; off <<= 1) {
        int a = 0; if (tid >= off) a = sI[tid - off];
        __syncthreads();
        sI[tid] += a;
        __syncthreads();
    }
    int run2 = tid ? sI[tid - 1] : 0;
    #pragma unroll
    for (int j = 0; j < 4; j++) {
        run2 += ld[j];
        int e = run2, s0 = e - ld[j];
        float sums = vcum[e] - vcum[s0];
        float cnt  = ncum[e] - ncum[s0];
        outAvg[b * 1024 + tid * 4 + j] = (cnt == 0.f) ? 0.f : sums / cnt;
    }
}

// ---------------- energy_emb: 1->256 conv, K=3, pad 1 ----------------
__global__ void emb_kernel(const float* __restrict__ avg, const float* __restrict__ wemb,
                           const float* __restrict__ bemb, float* __restrict__ out) {
    int id = blockIdx.x * 256 + threadIdx.x;
    int t4 = id & 255;
    int ch = (id >> 8) & 255;
    int b  = id >> 16;
    int t0 = t4 * 4;
    const float* a = avg + b * 1024;
    float am1 = (t0 - 1 >= 0) ? a[t0 - 1] : 0.f;
    float a0 = a[t0], a1 = a[t0 + 1], a2 = a[t0 + 2], a3 = a[t0 + 3];
    float a4 = (t0 + 4 < 1024) ? a[t0 + 4] : 0.f;
    float w0 = wemb[ch * 3], w1 = wemb[ch * 3 + 1], w2 = wemb[ch * 3 + 2], bb = bemb[ch];
    float4 o;
    o.x = bb + am1 * w0 + a0 * w1 + a1 * w2;
    o.y = bb + a0 * w0 + a1 * w1 + a2 * w2;
    o.z = bb + a1 * w0 + a2 * w1 + a3 * w2;
    o.w = bb + a2 * w0 + a3 * w1 + a4 * w2;
    *(float4*)(out + (((b << 8) | ch) << 10) + t0) = o;
}

// ---------------- launcher ----------------
extern "C" void kernel_launch(void* const* d_in, const int* in_sizes, int n_in,
                              void* d_out, int out_size, void* d_ws, size_t ws_size,
                              hipStream_t stream) {
    const float* x      = (const float*)d_in[0];
    const float* target = (const float*)d_in[1];
    const int*   dr     = (const int*)d_in[2];
    const unsigned char* mask = (const unsigned char*)d_in[3];
    const float* w1   = (const float*)d_in[4];
    const float* b1   = (const float*)d_in[5];
    const float* g1   = (const float*)d_in[6];
    const float* be1  = (const float*)d_in[7];
    const float* w2   = (const float*)d_in[8];
    const float* b2   = (const float*)d_in[9];
    const float* g2   = (const float*)d_in[10];
    const float* be2  = (const float*)d_in[11];
    const float* wlin = (const float*)d_in[12];
    const float* blin = (const float*)d_in[13];
    const float* wemb = (const float*)d_in[14];
    const float* bemb = (const float*)d_in[15];

    char* ws = (char*)d_ws;
    unsigned short* xbp  = (unsigned short*)ws;                    // 33,685,504 B  [32][1028][512]
    unsigned short* h1bp = (unsigned short*)(ws + 33685504);       // 16,842,752 B  [32][1028][256]
    unsigned short* wr1  = (unsigned short*)(ws + 50528256);       //  1,310,720 B
    unsigned short* wr2  = (unsigned short*)(ws + 51838976);       //    655,360 B

    float* outPred = (float*)d_out;            // 32768
    float* outAvg  = outPred + 32768;          // 32768
    float* outEmb  = outPred + 65536;          // 8,388,608

    // 1. cast+pad x; zero halos of both padded buffers
    cast_pad_x<<<8192, 256, 0, stream>>>(x, xbp);
    zero_pads<<<32, 256, 0, stream>>>(xbp, 512);
    zero_pads<<<16, 256, 0, stream>>>(h1bp, 256);
    // 2. weight prep
    prep_w<<<2560, 256, 0, stream>>>(w1, wr1, 512, 256 * 512 * 5);
    prep_w<<<1280, 256, 0, stream>>>(w2, wr2, 256, 256 * 256 * 5);
    // 3. conv1 + bias + leaky + LN1 -> padded bf16
    gemm_conv_fused<512, false><<<128, 512, 0, stream>>>(
        xbp, wr1, b1, g1, be1, wlin, blin, mask, h1bp, outPred);
    // 4. conv2 + bias + leaky + LN2 + linear + mask -> energy_pred
    gemm_conv_fused<256, true><<<128, 512, 0, stream>>>(
        h1bp, wr2, b2, g2, be2, wlin, blin, mask, h1bp, outPred);
    // 5. averaged target -> output 1
    avg_kernel<<<32, 256, 0, stream>>>(target, dr, outAvg);
    // 6. emb conv -> output 2
    emb_kernel<<<8192, 256, 0, stream>>>(outAvg, wemb, bemb, outEmb);
}

// Round 5
// 167.131 us; speedup vs baseline: 1.0031x; 1.0031x over previous
//
#include <hip/hip_runtime.h>

// ---------------- types & helpers ----------------
typedef __attribute__((ext_vector_type(8))) short short8;   // 8 bf16 (4 VGPRs)
typedef __attribute__((ext_vector_type(4))) float f32x4;

#define LEAKY_F 0.3f

typedef __attribute__((address_space(3))) void lds_t;
typedef __attribute__((address_space(1))) void gmem_t;
#define G2L(g, l) __builtin_amdgcn_global_load_lds((const gmem_t*)(g), (lds_t*)(l), 16, 0, 0)

__device__ __forceinline__ unsigned short f2bf(float f) {
    union { float f; unsigned u; } v; v.f = f;
    unsigned u = v.u;
    return (unsigned short)((u + 0x7fffu + ((u >> 16) & 1u)) >> 16);  // RNE
}
__device__ __forceinline__ float bf2f(unsigned short u) {
    union { unsigned u; float f; } v; v.u = ((unsigned)u) << 16; return v.f;
}

// ---------------- cast x f32 -> bf16 into padded [32][1028][512] ----------------
__global__ void cast_pad_x(const float* __restrict__ in, unsigned short* __restrict__ out) {
    int i = blockIdx.x * 256 + threadIdx.x;     // 8 elems per thread
    long g = (long)i * 8;
    int row = (int)(g >> 9);                    // 0..32767 (b*1024+t)
    int b = row >> 10;
    long o = ((long)(row + (b << 2) + 2) << 9) + (g & 511);
    const float4* p = (const float4*)(in + g);
    float4 a = p[0], c = p[1];
    union { unsigned short s[8]; uint4 v; } u;
    u.s[0] = f2bf(a.x); u.s[1] = f2bf(a.y); u.s[2] = f2bf(a.z); u.s[3] = f2bf(a.w);
    u.s[4] = f2bf(c.x); u.s[5] = f2bf(c.y); u.s[6] = f2bf(c.z); u.s[7] = f2bf(c.w);
    *(uint4*)(out + o) = u.v;
}

// ---------------- zero halo rows {0,1,1026,1027} of padded buffer ----------------
__global__ void zero_pads(unsigned short* __restrict__ p, int cin) {
    int j = blockIdx.x * 256 + threadIdx.x;     // one uint4 (8 elems) per thread
    int upb = cin >> 1;                          // units per batch (4 rows * cin / 8)
    int b = j / upb, rem = j % upb;
    int upr = cin >> 3;                          // units per row
    int r4 = rem / upr;
    int col = (rem % upr) * 8;
    int rowp = (r4 < 2) ? r4 : (r4 + 1024);
    *(uint4*)(p + ((long)b * 1028 + rowp) * cin + col) = make_uint4(0u, 0u, 0u, 0u);
}

// ---------------- weight rearrange: [CH][CIN][5] -> [CH][5*CIN] bf16 ----------------
__global__ void prep_w(const float* __restrict__ w, unsigned short* __restrict__ out, int CIN, int n) {
    int i = blockIdx.x * 256 + threadIdx.x;
    if (i >= n) return;
    int ch = i / (CIN * 5);
    int rem = i % (CIN * 5);
    int tap = rem / CIN;
    int cin = rem % CIN;
    out[ch * (5 * CIN) + tap * CIN + cin] = f2bf(w[(ch * CIN + cin) * 5 + tap]);
}

// ---------------- conv-as-GEMM, 256x256 tile, K-split 4-phase schedule ----------------
// A padded [32][1028][CIN] bf16; im2col linear. BM=256, BN=256, BK=64 (2x kh=32).
// 8 waves 2Mx4N (wave 128x64, acc 8x4). LDS: A[2buf][2kh][256r][32k], B same.
// Chunks per K-tile: {A-k0, B-k0, A-k1, B-k1}, staged in phases 0..3 of the
// previous tile. Phases (kh,mh): 0,1 consume only k0 chunks; 2,3 only k1.
// vmcnt(4) before phases 0 and 2 retires exactly the 4 oldest loads = the
// chunks that phase needs (in-order retirement). One barrier per phase.
template<int CIN, bool PRED>
__global__ __launch_bounds__(512, 2) void gemm_conv_fused(
    const unsigned short* __restrict__ A,
    const unsigned short* __restrict__ W,    // [256][5*CIN]
    const float* __restrict__ bias,
    const float* __restrict__ gam,
    const float* __restrict__ bet,
    const float* __restrict__ wlin,
    const float* __restrict__ blin,
    const unsigned char* __restrict__ mask,
    unsigned short* __restrict__ Yln,        // [32][1028][256] padded
    float* __restrict__ Ypred)               // [32768]
{
    constexpr int KW = 5 * CIN;
    constexpr int S  = KW / 64;
    __shared__ __align__(16) unsigned short smem[65536];   // 128 KB
    __shared__ float pb[1024];

    const int tid = threadIdx.x, lane = tid & 63, wid = tid >> 6;
    const int wm = wid >> 2, wn = wid & 3;
    const int blk = blockIdx.x;                 // 0..127
    const int bb = blk >> 2, tl0 = (blk & 3) << 8;
    const long rowbase = (long)bb * 1028 + tl0;

    // stage descriptors: chunk = 1024 units of 16B; unit u = c*512+tid,
    // r = u>>2 (row 0..255), q = u&3 (16B seg). LDS dest linear; global
    // source seg pre-swizzled with swz(r) = (r&3)^((r>>2)&3).
    long asrc[2], bsrc[2]; int udst[2];
    #pragma unroll
    for (int c = 0; c < 2; c++) {
        int u = c * 512 + tid;
        int r = u >> 2, q = u & 3;
        int sg = q ^ ((r & 3) ^ ((r >> 2) & 3));
        asrc[c] = (rowbase + r) * (long)CIN + sg * 8;
        bsrc[c] = (long)r * KW + sg * 8;
        udst[c] = u * 8;
    }

    auto stageA = [&](int buf, int kh, int kt) {
        const long k0 = (long)kt * 64 + kh * 32;
        #pragma unroll
        for (int c = 0; c < 2; c++)
            G2L(A + asrc[c] + k0, &smem[buf * 16384 + kh * 8192 + udst[c]]);
    };
    auto stageB = [&](int buf, int kh, int kt) {
        const long k0 = (long)kt * 64 + kh * 32;
        #pragma unroll
        for (int c = 0; c < 2; c++)
            G2L(W + bsrc[c] + k0, &smem[32768 + buf * 16384 + kh * 8192 + udst[c]]);
    };

    const int l15 = lane & 15, lhi = (lane >> 4) & 3;
    const int sw = (l15 & 3) ^ ((l15 >> 2) & 3);
    const int sloff = ((lhi ^ sw) & 3) << 3;

    f32x4 acc[8][4] = {};
    short8 af[4], bg[4];

#define RD_AF(buf, kh, mh)                                                      \
    _Pragma("unroll")                                                           \
    for (int j = 0; j < 4; j++)                                                 \
        af[j] = *(const short8*)&smem[(buf) * 16384 + (kh) * 8192 +             \
            (wm * 128 + (mh) * 64 + j * 16 + l15) * 32 + sloff];

#define RD_BG(buf, kh)                                                          \
    _Pragma("unroll")                                                           \
    for (int n = 0; n < 4; n++)                                                 \
        bg[n] = *(const short8*)&smem[32768 + (buf) * 16384 + (kh) * 8192 +     \
            (wn * 64 + n * 16 + l15) * 32 + sloff];

#define MFMA16(mh)                                                              \
    asm volatile("s_waitcnt lgkmcnt(0)" ::: "memory");                          \
    __builtin_amdgcn_sched_barrier(0);                                          \
    __builtin_amdgcn_s_setprio(1);                                              \
    _Pragma("unroll")                                                           \
    for (int j = 0; j < 4; j++)                                                 \
        _Pragma("unroll")                                                       \
        for (int n = 0; n < 4; n++)                                             \
            acc[(mh) * 4 + j][n] = __builtin_amdgcn_mfma_f32_16x16x32_bf16(     \
                af[j], bg[n], acc[(mh) * 4 + j][n], 0, 0, 0);                   \
    __builtin_amdgcn_s_setprio(0);                                              \
    __builtin_amdgcn_sched_barrier(0);

#define VMW4 asm volatile("s_waitcnt vmcnt(4)" ::: "memory")
#define BAR  __builtin_amdgcn_s_barrier()

    // prologue: tile 0's chunks in consumption order
    stageA(0, 0, 0); stageB(0, 0, 0); stageA(0, 1, 0); stageB(0, 1, 0);

    #pragma unroll 1
    for (int t = 0; t < S - 1; ++t) {
        const int b = t & 1, nb = b ^ 1;
        // phase 0 (kh0, mh0): needs A-k0,B-k0 of tile t
        VMW4; BAR;
        RD_BG(b, 0); RD_AF(b, 0, 0);
        stageA(nb, 0, t + 1);
        MFMA16(0);
        // phase 1 (kh0, mh1): chunk resident; pre-read overlaps barrier wait
        RD_AF(b, 0, 1);
        BAR;
        stageB(nb, 0, t + 1);
        MFMA16(1);
        // phase 2 (kh1, mh0): needs A-k1,B-k1 of tile t
        VMW4; BAR;
        RD_BG(b, 1); RD_AF(b, 1, 0);
        stageA(nb, 1, t + 1);
        MFMA16(0);
        // phase 3 (kh1, mh1)
        RD_AF(b, 1, 1);
        BAR;
        stageB(nb, 1, t + 1);
        MFMA16(1);
    }
    {   // tail tile S-1 (no staging)
        const int b = (S - 1) & 1;
        VMW4; BAR;
        RD_BG(b, 0); RD_AF(b, 0, 0);
        MFMA16(0);
        RD_AF(b, 0, 1);
        BAR;
        MFMA16(1);
        asm volatile("s_waitcnt vmcnt(0)" ::: "memory"); BAR;
        RD_BG(b, 1); RD_AF(b, 1, 0);
        MFMA16(0);
        RD_AF(b, 1, 1);
        BAR;
        MFMA16(1);
    }
#undef RD_AF
#undef RD_BG
#undef MFMA16
#undef VMW4
#undef BAR

    // ================= fused epilogue =================
    __syncthreads();
    if (tid < 256) {
        pb[tid]       = bias[tid];
        pb[256 + tid] = gam[tid];
        pb[512 + tid] = bet[tid];
        pb[768 + tid] = PRED ? wlin[tid] : 0.f;
    }
    __syncthreads();

    // acc -> LDS tile [256][256] bf16 (bias+leaky), 16B-unit XOR swizzle by row&7
    #pragma unroll
    for (int mm = 0; mm < 8; mm++) {
        #pragma unroll
        for (int n = 0; n < 4; n++) {
            const int col = wn * 64 + n * 16 + l15;
            const int u0 = col >> 3, ce = col & 7;
            const float bv = pb[col];
            #pragma unroll
            for (int q = 0; q < 4; q++) {
                const int row = wm * 128 + (mm >> 2) * 64 + (mm & 3) * 16 + lhi * 4 + q;
                float v = acc[mm][n][q] + bv;
                v = v > 0.f ? v : LEAKY_F * v;
                smem[row * 256 + ((u0 ^ (row & 7)) << 3) + ce] = f2bf(v);
            }
        }
    }
    __syncthreads();

    // per-row stats (4 lanes/row, two row-groups of 128)
    const int rid = tid >> 2, jq = tid & 3;
    #pragma unroll 1
    for (int ro = 0; ro < 2; ro++) {
        const int row = ro * 128 + rid;
        const int r7 = row & 7;
        float vals[8][8];
        float s1 = 0.f, s2 = 0.f, sgw = 0.f, sgc = 0.f, sbw = 0.f;
        #pragma unroll
        for (int u4 = 0; u4 < 8; u4++) {
            const int u = u4 * 4 + jq;
            short8 pk = *(const short8*)&smem[row * 256 + ((u ^ r7) << 3)];
            #pragma unroll
            for (int e = 0; e < 8; e++) {
                float v = bf2f((unsigned short)pk[e]);
                vals[u4][e] = v;
                s1 += v; s2 += v * v;
            }
            if (PRED) {
                const int c0 = u * 8;
                f32x4 ga = *(const f32x4*)&pb[256 + c0], gb = *(const f32x4*)&pb[260 + c0];
                f32x4 wa = *(const f32x4*)&pb[768 + c0], wb = *(const f32x4*)&pb[772 + c0];
                f32x4 ba = *(const f32x4*)&pb[512 + c0], bb2 = *(const f32x4*)&pb[516 + c0];
                #pragma unroll
                for (int e = 0; e < 4; e++) {
                    sgw += vals[u4][e] * ga[e] * wa[e] + vals[u4][e + 4] * gb[e] * wb[e];
                    sgc += ga[e] * wa[e] + gb[e] * wb[e];
                    sbw += ba[e] * wa[e] + bb2[e] * wb[e];
                }
            }
        }
        s1 += __shfl_xor(s1, 1); s1 += __shfl_xor(s1, 2);
        s2 += __shfl_xor(s2, 1); s2 += __shfl_xor(s2, 2);
        const float mean = s1 * (1.f / 256.f);
        const float var  = s2 * (1.f / 256.f) - mean * mean;
        const float rs   = rsqrtf(var + 1e-5f);
        const long grow  = (long)blk * 256 + row;

        if (PRED) {
            sgw += __shfl_xor(sgw, 1); sgw += __shfl_xor(sgw, 2);
            sgc += __shfl_xor(sgc, 1); sgc += __shfl_xor(sgc, 2);
            sbw += __shfl_xor(sbw, 1); sbw += __shfl_xor(sbw, 2);
            if (jq == 0) {
                float p = rs * (sgw - mean * sgc) + sbw + blin[0];
                if (mask[grow]) p = 0.f;
                Ypred[grow] = p;
            }
        } else {
            const int bnum = (int)(grow >> 10);
            const long prow = grow + (bnum << 2) + 2;
            #pragma unroll
            for (int u4 = 0; u4 < 8; u4++) {
                const int u = u4 * 4 + jq;
                const int c0 = u * 8;
                f32x4 ga = *(const f32x4*)&pb[256 + c0], gb = *(const f32x4*)&pb[260 + c0];
                f32x4 ba = *(const f32x4*)&pb[512 + c0], bb2 = *(const f32x4*)&pb[516 + c0];
                union { unsigned short s[8]; uint4 v; } o;
                #pragma unroll
                for (int e = 0; e < 4; e++) {
                    o.s[e]     = f2bf((vals[u4][e]     - mean) * rs * ga[e] + ba[e]);
                    o.s[e + 4] = f2bf((vals[u4][e + 4] - mean) * rs * gb[e] + bb2[e]);
                }
                *(uint4*)(Yln + prow * 256 + c0) = o.v;
            }
        }
    }
}

// ---------------- averaged-over-durations (exact reference algorithm) ----------------
__global__ void avg_kernel(const float* __restrict__ target, const int* __restrict__ dr,
                           float* __restrict__ outAvg) {
    __shared__ float vcum[4097];
    __shared__ float ncum[4097];
    __shared__ float sS[256];
    __shared__ float sC[256];
    __shared__ int   sI[256];
    int b = blockIdx.x, tid = threadIdx.x;
    const float* tb = target + b * 4096;
    float lv[16]; float ls = 0.f, lc = 0.f;
    #pragma unroll
    for (int j = 0; j < 16; j++) {
        float v = tb[tid * 16 + j]; lv[j] = v; ls += v; lc += (v != 0.f) ? 1.f : 0.f;
    }
    sS[tid] = ls; sC[tid] = lc;
    __syncthreads();
    for (int off = 1; off < 256; off <<= 1) {
        float a = 0.f, c2 = 0.f;
        if (tid >= off) { a = sS[tid - off]; c2 = sC[tid - off]; }
        __syncthreads();
        sS[tid] += a; sC[tid] += c2;
        __syncthreads();
    }
    float pS = tid ? sS[tid - 1] : 0.f, pC = tid ? sC[tid - 1] : 0.f;
    if (tid == 0) { vcum[0] = 0.f; ncum[0] = 0.f; }
    float run = pS, runc = pC;
    #pragma unroll
    for (int j = 0; j < 16; j++) {
        run += lv[j]; runc += (lv[j] != 0.f) ? 1.f : 0.f;
        vcum[tid * 16 + j + 1] = run; ncum[tid * 16 + j + 1] = runc;
    }
    const int* db = dr + b * 1024;
    int ld[4]; int lsum = 0;
    #pragma unroll
    for (int j = 0; j < 4; j++) { ld[j] = db[tid * 4 + j]; lsum += ld[j]; }
    sI[tid] = lsum;
    __syncthreads();
    for (int off = 1; off < 256; off <<= 1) {
        int a = 0; if (tid >= off) a = sI[tid - off];
        __syncthreads();
        sI[tid] += a;
        __syncthreads();
    }
    int run2 = tid ? sI[tid - 1] : 0;
    #pragma unroll
    for (int j = 0; j < 4; j++) {
        run2 += ld[j];
        int e = run2, s0 = e - ld[j];
        float sums = vcum[e] - vcum[s0];
        float cnt  = ncum[e] - ncum[s0];
        outAvg[b * 1024 + tid * 4 + j] = (cnt == 0.f) ? 0.f : sums / cnt;
    }
}

// ---------------- energy_emb: 1->256 conv, K=3, pad 1 ----------------
__global__ void emb_kernel(const float* __restrict__ avg, const float* __restrict__ wemb,
                           const float* __restrict__ bemb, float* __restrict__ out) {
    int id = blockIdx.x * 256 + threadIdx.x;
    int t4 = id & 255;
    int ch = (id >> 8) & 255;
    int b  = id >> 16;
    int t0 = t4 * 4;
    const float* a = avg + b * 1024;
    float am1 = (t0 - 1 >= 0) ? a[t0 - 1] : 0.f;
    float a0 = a[t0], a1 = a[t0 + 1], a2 = a[t0 + 2], a3 = a[t0 + 3];
    float a4 = (t0 + 4 < 1024) ? a[t0 + 4] : 0.f;
    float w0 = wemb[ch * 3], w1 = wemb[ch * 3 + 1], w2 = wemb[ch * 3 + 2], bb = bemb[ch];
    float4 o;
    o.x = bb + am1 * w0 + a0 * w1 + a1 * w2;
    o.y = bb + a0 * w0 + a1 * w1 + a2 * w2;
    o.z = bb + a1 * w0 + a2 * w1 + a3 * w2;
    o.w = bb + a2 * w0 + a3 * w1 + a4 * w2;
    *(float4*)(out + (((b << 8) | ch) << 10) + t0) = o;
}

// ---------------- launcher ----------------
extern "C" void kernel_launch(void* const* d_in, const int* in_sizes, int n_in,
                              void* d_out, int out_size, void* d_ws, size_t ws_size,
                              hipStream_t stream) {
    const float* x      = (const float*)d_in[0];
    const float* target = (const float*)d_in[1];
    const int*   dr     = (const int*)d_in[2];
    const unsigned char* mask = (const unsigned char*)d_in[3];
    const float* w1   = (const float*)d_in[4];
    const float* b1   = (const float*)d_in[5];
    const float* g1   = (const float*)d_in[6];
    const float* be1  = (const float*)d_in[7];
    const float* w2   = (const float*)d_in[8];
    const float* b2   = (const float*)d_in[9];
    const float* g2   = (const float*)d_in[10];
    const float* be2  = (const float*)d_in[11];
    const float* wlin = (const float*)d_in[12];
    const float* blin = (const float*)d_in[13];
    const float* wemb = (const float*)d_in[14];
    const float* bemb = (const float*)d_in[15];

    char* ws = (char*)d_ws;
    unsigned short* xbp  = (unsigned short*)ws;                    // 33,685,504 B  [32][1028][512]
    unsigned short* h1bp = (unsigned short*)(ws + 33685504);       // 16,842,752 B  [32][1028][256]
    unsigned short* wr1  = (unsigned short*)(ws + 50528256);       //  1,310,720 B
    unsigned short* wr2  = (unsigned short*)(ws + 51838976);       //    655,360 B

    float* outPred = (float*)d_out;            // 32768
    float* outAvg  = outPred + 32768;          // 32768
    float* outEmb  = outPred + 65536;          // 8,388,608

    // 1. cast+pad x; zero halos of both padded buffers
    cast_pad_x<<<8192, 256, 0, stream>>>(x, xbp);
    zero_pads<<<32, 256, 0, stream>>>(xbp, 512);
    zero_pads<<<16, 256, 0, stream>>>(h1bp, 256);
    // 2. weight prep
    prep_w<<<2560, 256, 0, stream>>>(w1, wr1, 512, 256 * 512 * 5);
    prep_w<<<1280, 256, 0, stream>>>(w2, wr2, 256, 256 * 256 * 5);
    // 3. conv1 + bias + leaky + LN1 -> padded bf16
    gemm_conv_fused<512, false><<<128, 512, 0, stream>>>(
        xbp, wr1, b1, g1, be1, wlin, blin, mask, h1bp, outPred);
    // 4. conv2 + bias + leaky + LN2 + linear + mask -> energy_pred
    gemm_conv_fused<256, true><<<128, 512, 0, stream>>>(
        h1bp, wr2, b2, g2, be2, wlin, blin, mask, h1bp, outPred);
    // 5. averaged target -> output 1
    avg_kernel<<<32, 256, 0, stream>>>(target, dr, outAvg);
    // 6. emb conv -> output 2
    emb_kernel<<<8192, 256, 0, stream>>>(outAvg, wemb, bemb, outEmb);
}

// Round 6
// 135.704 us; speedup vs baseline: 1.2353x; 1.2316x over previous
//
#include <hip/hip_runtime.h>

// ---------------- types & helpers ----------------
typedef __attribute__((ext_vector_type(8))) short short8;   // 8 bf16 (4 VGPRs)
typedef __attribute__((ext_vector_type(4))) float f32x4;

#define LEAKY_F 0.3f

typedef __attribute__((address_space(3))) void lds_t;
typedef __attribute__((address_space(1))) void gmem_t;
#define G2L(g, l) __builtin_amdgcn_global_load_lds((const gmem_t*)(g), (lds_t*)(l), 16, 0, 0)

__device__ __forceinline__ unsigned short f2bf(float f) {
    union { float f; unsigned u; } v; v.f = f;
    unsigned u = v.u;
    return (unsigned short)((u + 0x7fffu + ((u >> 16) & 1u)) >> 16);  // RNE
}
__device__ __forceinline__ float bf2f(unsigned short u) {
    union { unsigned u; float f; } v; v.u = ((unsigned)u) << 16; return v.f;
}

// ---------------- cast x f32 -> bf16 into padded [32][1028][512] ----------------
__global__ void cast_pad_x(const float* __restrict__ in, unsigned short* __restrict__ out) {
    int i = blockIdx.x * 256 + threadIdx.x;     // 8 elems per thread
    long g = (long)i * 8;
    int row = (int)(g >> 9);                    // 0..32767 (b*1024+t)
    int b = row >> 10;
    long o = ((long)(row + (b << 2) + 2) << 9) + (g & 511);
    const float4* p = (const float4*)(in + g);
    float4 a = p[0], c = p[1];
    union { unsigned short s[8]; uint4 v; } u;
    u.s[0] = f2bf(a.x); u.s[1] = f2bf(a.y); u.s[2] = f2bf(a.z); u.s[3] = f2bf(a.w);
    u.s[4] = f2bf(c.x); u.s[5] = f2bf(c.y); u.s[6] = f2bf(c.z); u.s[7] = f2bf(c.w);
    *(uint4*)(out + o) = u.v;
}

// ---------------- zero halo rows {0,1,1026,1027} of padded buffer ----------------
__global__ void zero_pads(unsigned short* __restrict__ p, int cin) {
    int j = blockIdx.x * 256 + threadIdx.x;     // one uint4 (8 elems) per thread
    int upb = cin >> 1;                          // units per batch (4 rows * cin / 8)
    int b = j / upb, rem = j % upb;
    int upr = cin >> 3;                          // units per row
    int r4 = rem / upr;
    int col = (rem % upr) * 8;
    int rowp = (r4 < 2) ? r4 : (r4 + 1024);
    *(uint4*)(p + ((long)b * 1028 + rowp) * cin + col) = make_uint4(0u, 0u, 0u, 0u);
}

// ---------------- weight rearrange: [CH][CIN][5] -> [CH][5*CIN] bf16 ----------------
__global__ void prep_w(const float* __restrict__ w, unsigned short* __restrict__ out, int CIN, int n) {
    int i = blockIdx.x * 256 + threadIdx.x;
    if (i >= n) return;
    int ch = i / (CIN * 5);
    int rem = i % (CIN * 5);
    int tap = rem / CIN;
    int cin = rem % CIN;
    out[ch * (5 * CIN) + tap * CIN + cin] = f2bf(w[(ch * CIN + cin) * 5 + tap]);
}

// ---------------- conv-as-GEMM + fused epilogue ----------------
// A padded [32][1028][CIN] bf16; im2col linear. Tile 128x256, BK=64, 8 waves
// (2Mx4N, wave 64x64, acc 4x4). 3-deep LDS ring, ONE barrier/step, all 16
// ds_reads (kh0+kh1) issued up front, counted lgkmcnt(8)/(0) splits, counted
// vmcnt(6), setprio around each 16-MFMA cluster.
template<int CIN, bool PRED>
__global__ __launch_bounds__(512, 2) void gemm_conv_fused(
    const unsigned short* __restrict__ A,
    const unsigned short* __restrict__ W,    // [256][5*CIN]
    const float* __restrict__ bias,
    const float* __restrict__ gam,
    const float* __restrict__ bet,
    const float* __restrict__ wlin,
    const float* __restrict__ blin,
    const unsigned char* __restrict__ mask,
    unsigned short* __restrict__ Yln,        // [32][1028][256] padded
    float* __restrict__ Ypred)               // [32768]
{
    constexpr int KW = 5 * CIN;
    constexpr int S  = KW / 64;
    constexpr int ASLOT = 128 * 64;          // elems (16 KB)
    constexpr int BSLOT = 256 * 64;          // elems (32 KB)
    __shared__ __align__(16) unsigned short smem[3 * (ASLOT + BSLOT)];  // 144 KB
    __shared__ float pb[1024];

    const int tid = threadIdx.x, lane = tid & 63, wid = tid >> 6;
    const int wm = wid >> 2, wn = wid & 3;
    const int blk = blockIdx.x;
    const int bb = blk >> 3, tl0 = (blk & 7) << 7;
    const long rowbase = (long)bb * 1028 + tl0;

    // staging descriptors: LDS dest linear; source seg pre-swizzled (seg ^= r&7)
    long asrc[2]; int adst[2];
    #pragma unroll
    for (int c = 0; c < 2; c++) {
        int u = ((c * 8 + wid) << 6) + lane;
        int r = u >> 3, sg = (u & 7) ^ (r & 7);
        asrc[c] = (rowbase + r) * (long)CIN + sg * 8;
        adst[c] = (c * 8 + wid) << 9;
    }
    long bsrc[4]; int bdst[4];
    #pragma unroll
    for (int c = 0; c < 4; c++) {
        int u = ((c * 8 + wid) << 6) + lane;
        int r = u >> 3, sg = (u & 7) ^ (r & 7);
        bsrc[c] = (long)r * KW + sg * 8;
        bdst[c] = (c * 8 + wid) << 9;
    }

    auto stage = [&](int t, int slot) {
        const int k0 = t * 64;
        unsigned short* a = smem + slot * ASLOT;
        unsigned short* b = smem + 3 * ASLOT + slot * BSLOT;
        #pragma unroll
        for (int c = 0; c < 2; c++) G2L(A + asrc[c] + k0, a + adst[c]);
        #pragma unroll
        for (int c = 0; c < 4; c++) G2L(W + bsrc[c] + k0, b + bdst[c]);
    };

    const int l15 = lane & 15, lhi = (lane >> 4) & 3, sw = l15 & 7;
    const int arow = (wm * 64 + l15) * 64;
    const int brow = (wn * 64 + l15) * 64;
    const int sg0 = ((lhi ^ sw) & 7) << 3;          // kh=0 seg offset
    const int sg1 = (((4 | lhi) ^ sw) & 7) << 3;    // kh=1 seg offset

    f32x4 acc[4][4] = {};

    // prologue: tiles 0 and 1 in flight (6 loads each)
    stage(0, 0);
    stage(1, 1);

    int rb = 0;
    #pragma unroll 1
    for (int t = 0; t < S; ++t) {
        if (t < S - 1) { asm volatile("s_waitcnt vmcnt(6)" ::: "memory"); }
        else           { asm volatile("s_waitcnt vmcnt(0)" ::: "memory"); }
        __builtin_amdgcn_sched_barrier(0);
        __builtin_amdgcn_s_barrier();
        __builtin_amdgcn_sched_barrier(0);

        const unsigned short* ab = smem + rb * ASLOT;
        const unsigned short* bp = smem + 3 * ASLOT + rb * BSLOT;

        short8 af0[4], bg0[4], af1[4], bg1[4];
        #pragma unroll
        for (int m = 0; m < 4; m++)
            af0[m] = *(const short8*)&ab[arow + m * 1024 + sg0];
        #pragma unroll
        for (int n = 0; n < 4; n++)
            bg0[n] = *(const short8*)&bp[brow + n * 1024 + sg0];

        if (t + 2 < S) stage(t + 2, (rb == 0) ? 2 : (rb - 1));

        #pragma unroll
        for (int m = 0; m < 4; m++)
            af1[m] = *(const short8*)&ab[arow + m * 1024 + sg1];
        #pragma unroll
        for (int n = 0; n < 4; n++)
            bg1[n] = *(const short8*)&bp[brow + n * 1024 + sg1];

        asm volatile("s_waitcnt lgkmcnt(8)" ::: "memory");
        __builtin_amdgcn_sched_barrier(0);
        __builtin_amdgcn_s_setprio(1);
        #pragma unroll
        for (int m = 0; m < 4; m++)
            #pragma unroll
            for (int n = 0; n < 4; n++)
                acc[m][n] = __builtin_amdgcn_mfma_f32_16x16x32_bf16(af0[m], bg0[n], acc[m][n], 0, 0, 0);
        __builtin_amdgcn_s_setprio(0);
        __builtin_amdgcn_sched_barrier(0);

        asm volatile("s_waitcnt lgkmcnt(0)" ::: "memory");
        __builtin_amdgcn_sched_barrier(0);
        __builtin_amdgcn_s_setprio(1);
        #pragma unroll
        for (int m = 0; m < 4; m++)
            #pragma unroll
            for (int n = 0; n < 4; n++)
                acc[m][n] = __builtin_amdgcn_mfma_f32_16x16x32_bf16(af1[m], bg1[n], acc[m][n], 0, 0, 0);
        __builtin_amdgcn_s_setprio(0);
        __builtin_amdgcn_sched_barrier(0);

        rb = (rb == 2) ? 0 : (rb + 1);
    }

    // ================= fused epilogue =================
    __syncthreads();   // safe to reuse smem

    if (tid < 256) {
        pb[tid]       = bias[tid];
        pb[256 + tid] = gam[tid];
        pb[512 + tid] = bet[tid];
        pb[768 + tid] = PRED ? wlin[tid] : 0.f;
    }
    __syncthreads();

    // acc -> LDS tile [128][256] bf16 (bias+leaky), 16B-unit XOR swizzle
    unsigned short* tile = smem;
    #pragma unroll
    for (int n = 0; n < 4; n++) {
        const int col = wn * 64 + n * 16 + l15;
        const float bv = pb[col];
        const int u0 = col >> 3, ce = col & 7;
        #pragma unroll
        for (int m = 0; m < 4; m++) {
            const int rA = wm * 64 + m * 16 + lhi * 4;
            #pragma unroll
            for (int q = 0; q < 4; q++) {
                const int row = rA + q;
                float v = acc[m][n][q] + bv;
                v = v > 0.f ? v : LEAKY_F * v;
                tile[row * 256 + ((u0 ^ (row & 7)) << 3) + ce] = f2bf(v);
            }
        }
    }
    __syncthreads();

    // per-row reduce (4 lanes/row) & output
    const int rid = tid >> 2, jq = tid & 3;
    const int r7 = rid & 7;
    float vals[8][8];
    float s1 = 0.f, s2 = 0.f, sgw = 0.f, sgc = 0.f, sbw = 0.f;
    #pragma unroll
    for (int u4 = 0; u4 < 8; u4++) {
        const int u = u4 * 4 + jq;
        short8 pk = *(const short8*)&tile[rid * 256 + ((u ^ r7) << 3)];
        #pragma unroll
        for (int e = 0; e < 8; e++) {
            float v = bf2f((unsigned short)pk[e]);
            vals[u4][e] = v;
            s1 += v; s2 += v * v;
        }
        if (PRED) {
            const int c0 = u * 8;
            f32x4 ga = *(const f32x4*)&pb[256 + c0], gb = *(const f32x4*)&pb[260 + c0];
            f32x4 wa = *(const f32x4*)&pb[768 + c0], wb = *(const f32x4*)&pb[772 + c0];
            f32x4 ba = *(const f32x4*)&pb[512 + c0], bb2 = *(const f32x4*)&pb[516 + c0];
            #pragma unroll
            for (int e = 0; e < 4; e++) {
                sgw += vals[u4][e] * ga[e] * wa[e] + vals[u4][e + 4] * gb[e] * wb[e];
                sgc += ga[e] * wa[e] + gb[e] * wb[e];
                sbw += ba[e] * wa[e] + bb2[e] * wb[e];
            }
        }
    }
    s1 += __shfl_xor(s1, 1); s1 += __shfl_xor(s1, 2);
    s2 += __shfl_xor(s2, 1); s2 += __shfl_xor(s2, 2);
    const float mean = s1 * (1.f / 256.f);
    const float var  = s2 * (1.f / 256.f) - mean * mean;
    const float rs   = rsqrtf(var + 1e-5f);
    const long grow  = (long)blk * 128 + rid;

    if (PRED) {
        sgw += __shfl_xor(sgw, 1); sgw += __shfl_xor(sgw, 2);
        sgc += __shfl_xor(sgc, 1); sgc += __shfl_xor(sgc, 2);
        sbw += __shfl_xor(sbw, 1); sbw += __shfl_xor(sbw, 2);
        if (jq == 0) {
            float p = rs * (sgw - mean * sgc) + sbw + blin[0];
            if (mask[grow]) p = 0.f;
            Ypred[grow] = p;
        }
    } else {
        const int bnum = (int)(grow >> 10);
        const long prow = grow + (bnum << 2) + 2;
        #pragma unroll
        for (int u4 = 0; u4 < 8; u4++) {
            const int u = u4 * 4 + jq;
            const int c0 = u * 8;
            f32x4 ga = *(const f32x4*)&pb[256 + c0], gb = *(const f32x4*)&pb[260 + c0];
            f32x4 ba = *(const f32x4*)&pb[512 + c0], bb2 = *(const f32x4*)&pb[516 + c0];
            union { unsigned short s[8]; uint4 v; } o;
            #pragma unroll
            for (int e = 0; e < 4; e++) {
                o.s[e]     = f2bf((vals[u4][e]     - mean) * rs * ga[e] + ba[e]);
                o.s[e + 4] = f2bf((vals[u4][e + 4] - mean) * rs * gb[e] + bb2[e]);
            }
            *(uint4*)(Yln + prow * 256 + c0) = o.v;
        }
    }
}

// ---------------- averaged-over-durations (exact reference algorithm) ----------------
__global__ void avg_kernel(const float* __restrict__ target, const int* __restrict__ dr,
                           float* __restrict__ outAvg) {
    __shared__ float vcum[4097];
    __shared__ float ncum[4097];
    __shared__ float sS[256];
    __shared__ float sC[256];
    __shared__ int   sI[256];
    int b = blockIdx.x, tid = threadIdx.x;
    const float* tb = target + b * 4096;
    float lv[16]; float ls = 0.f, lc = 0.f;
    #pragma unroll
    for (int j = 0; j < 16; j++) {
        float v = tb[tid * 16 + j]; lv[j] = v; ls += v; lc += (v != 0.f) ? 1.f : 0.f;
    }
    sS[tid] = ls; sC[tid] = lc;
    __syncthreads();
    for (int off = 1; off < 256; off <<= 1) {
        float a = 0.f, c2 = 0.f;
        if (tid >= off) { a = sS[tid - off]; c2 = sC[tid - off]; }
        __syncthreads();
        sS[tid] += a; sC[tid] += c2;
        __syncthreads();
    }
    float pS = tid ? sS[tid - 1] : 0.f, pC = tid ? sC[tid - 1] : 0.f;
    if (tid == 0) { vcum[0] = 0.f; ncum[0] = 0.f; }
    float run = pS, runc = pC;
    #pragma unroll
    for (int j = 0; j < 16; j++) {
        run += lv[j]; runc += (lv[j] != 0.f) ? 1.f : 0.f;
        vcum[tid * 16 + j + 1] = run; ncum[tid * 16 + j + 1] = runc;
    }
    const int* db = dr + b * 1024;
    int ld[4]; int lsum = 0;
    #pragma unroll
    for (int j = 0; j < 4; j++) { ld[j] = db[tid * 4 + j]; lsum += ld[j]; }
    sI[tid] = lsum;
    __syncthreads();
    for (int off = 1; off < 256; off <<= 1) {
        int a = 0; if (tid >= off) a = sI[tid - off];
        __syncthreads();
        sI[tid] += a;
        __syncthreads();
    }
    int run2 = tid ? sI[tid - 1] : 0;
    #pragma unroll
    for (int j = 0; j < 4; j++) {
        run2 += ld[j];
        int e = run2, s0 = e - ld[j];
        float sums = vcum[e] - vcum[s0];
        float cnt  = ncum[e] - ncum[s0];
        outAvg[b * 1024 + tid * 4 + j] = (cnt == 0.f) ? 0.f : sums / cnt;
    }
}

// ---------------- energy_emb: 1->256 conv, K=3, pad 1 ----------------
__global__ void emb_kernel(const float* __restrict__ avg, const float* __restrict__ wemb,
                           const float* __restrict__ bemb, float* __restrict__ out) {
    int id = blockIdx.x * 256 + threadIdx.x;
    int t4 = id & 255;
    int ch = (id >> 8) & 255;
    int b  = id >> 16;
    int t0 = t4 * 4;
    const float* a = avg + b * 1024;
    float am1 = (t0 - 1 >= 0) ? a[t0 - 1] : 0.f;
    float a0 = a[t0], a1 = a[t0 + 1], a2 = a[t0 + 2], a3 = a[t0 + 3];
    float a4 = (t0 + 4 < 1024) ? a[t0 + 4] : 0.f;
    float w0 = wemb[ch * 3], w1 = wemb[ch * 3 + 1], w2 = wemb[ch * 3 + 2], bb = bemb[ch];
    float4 o;
    o.x = bb + am1 * w0 + a0 * w1 + a1 * w2;
    o.y = bb + a0 * w0 + a1 * w1 + a2 * w2;
    o.z = bb + a1 * w0 + a2 * w1 + a3 * w2;
    o.w = bb + a2 * w0 + a3 * w1 + a4 * w2;
    *(float4*)(out + (((b << 8) | ch) << 10) + t0) = o;
}

// ---------------- launcher ----------------
extern "C" void kernel_launch(void* const* d_in, const int* in_sizes, int n_in,
                              void* d_out, int out_size, void* d_ws, size_t ws_size,
                              hipStream_t stream) {
    const float* x      = (const float*)d_in[0];
    const float* target = (const float*)d_in[1];
    const int*   dr     = (const int*)d_in[2];
    const unsigned char* mask = (const unsigned char*)d_in[3];
    const float* w1   = (const float*)d_in[4];
    const float* b1   = (const float*)d_in[5];
    const float* g1   = (const float*)d_in[6];
    const float* be1  = (const float*)d_in[7];
    const float* w2   = (const float*)d_in[8];
    const float* b2   = (const float*)d_in[9];
    const float* g2   = (const float*)d_in[10];
    const float* be2  = (const float*)d_in[11];
    const float* wlin = (const float*)d_in[12];
    const float* blin = (const float*)d_in[13];
    const float* wemb = (const float*)d_in[14];
    const float* bemb = (const float*)d_in[15];

    char* ws = (char*)d_ws;
    unsigned short* xbp  = (unsigned short*)ws;                    // 33,685,504 B  [32][1028][512]
    unsigned short* h1bp = (unsigned short*)(ws + 33685504);       // 16,842,752 B  [32][1028][256]
    unsigned short* wr1  = (unsigned short*)(ws + 50528256);       //  1,310,720 B
    unsigned short* wr2  = (unsigned short*)(ws + 51838976);       //    655,360 B

    float* outPred = (float*)d_out;            // 32768
    float* outAvg  = outPred + 32768;          // 32768
    float* outEmb  = outPred + 65536;          // 8,388,608

    // 1. cast+pad x; zero halos of both padded buffers
    cast_pad_x<<<8192, 256, 0, stream>>>(x, xbp);
    zero_pads<<<32, 256, 0, stream>>>(xbp, 512);
    zero_pads<<<16, 256, 0, stream>>>(h1bp, 256);
    // 2. weight prep
    prep_w<<<2560, 256, 0, stream>>>(w1, wr1, 512, 256 * 512 * 5);
    prep_w<<<1280, 256, 0, stream>>>(w2, wr2, 256, 256 * 256 * 5);
    // 3. conv1 + bias + leaky + LN1 -> padded bf16
    gemm_conv_fused<512, false><<<256, 512, 0, stream>>>(
        xbp, wr1, b1, g1, be1, wlin, blin, mask, h1bp, outPred);
    // 4. conv2 + bias + leaky + LN2 + linear + mask -> energy_pred
    gemm_conv_fused<256, true><<<256, 512, 0, stream>>>(
        h1bp, wr2, b2, g2, be2, wlin, blin, mask, h1bp, outPred);
    // 5. averaged target -> output 1
    avg_kernel<<<32, 256, 0, stream>>>(target, dr, outAvg);
    // 6. emb conv -> output 2
    emb_kernel<<<8192, 256, 0, stream>>>(outAvg, wemb, bemb, outEmb);
}